// Round 5
// baseline (224.716 us; speedup 1.0000x reference)
//
#include <hip/hip_runtime.h>
#include <hip/hip_bf16.h>

#define BATCH 16384
#define NH 1024
#define NF 39
#define CCLD 72
#define KX 2432      // GEMM1 K: [0:13 conts][13:16 pad0][16:1680 cate flat][1680:2421 pairs][2421:2432 pad0]
#define NPAIR 741

typedef __attribute__((ext_vector_type(8))) short bf16x8;
typedef __attribute__((ext_vector_type(4))) float f32x4;

typedef const __attribute__((address_space(1))) unsigned int* gptr_t;
typedef __attribute__((address_space(3))) unsigned int* lptr_t;

__device__ __forceinline__ float bf2f(unsigned short u) {
  union { unsigned int i; float f; } c; c.i = ((unsigned int)u) << 16; return c.f;
}
__device__ __forceinline__ unsigned short f2bf(float f) {
  union { float f; unsigned int i; } c; c.f = f;
  unsigned int r = c.i + 0x7FFFu + ((c.i >> 16) & 1u);
  return (unsigned short)(r >> 16);
}

// ---- W1t'(NH x KX bf16): row-remapped transpose of [M13 | W1 cate rows | W1 pair rows]
__global__ __launch_bounds__(256) void build_w1t_kernel(
    const float* __restrict__ W1, const float* __restrict__ emb,
    unsigned short* __restrict__ dst) {
  __shared__ float tile[32][33];
  int kb = blockIdx.x * 32, nb = blockIdx.y * 32;
  int tx = threadIdx.x & 31, ty = threadIdx.x >> 5;
#pragma unroll
  for (int i = 0; i < 32; i += 8) {
    int k = kb + ty + i;
    float v = 0.f;
    if (k < 13) {
      float s = 0.f;
#pragma unroll 8
      for (int d = 0; d < 64; ++d)
        s += emb[k * 64 + d] * W1[(size_t)(k * 64 + d) * NH + nb + tx];
      v = s;
    } else if (k >= 16 && k < 1680) {
      v = W1[(size_t)(832 + k - 16) * NH + nb + tx];
    } else if (k >= 1680 && k < 1680 + NPAIR) {
      v = W1[(size_t)(2496 + k - 1680) * NH + nb + tx];
    }
    tile[ty + i][tx] = v;
  }
  __syncthreads();
#pragma unroll
  for (int i = 0; i < 32; i += 8)
    dst[(size_t)(nb + ty + i) * KX + kb + tx] = f2bf(tile[tx][ty + i]);
}

// ---- W transpose + bf16 cast (square, for W2)
__global__ __launch_bounds__(256) void transpose_cast_kernel(
    const float* __restrict__ src, unsigned short* __restrict__ dst,
    int K, int N, int Kpad) {
  __shared__ float tile[32][33];
  int kb = blockIdx.x * 32, nb = blockIdx.y * 32;
  int tx = threadIdx.x & 31, ty = threadIdx.x >> 5;
#pragma unroll
  for (int i = 0; i < 32; i += 8) {
    int k = kb + ty + i;
    tile[ty + i][tx] = (k < K) ? src[(size_t)k * N + nb + tx] : 0.f;
  }
  __syncthreads();
#pragma unroll
  for (int i = 0; i < 32; i += 8) {
    int n = nb + ty + i, k = kb + tx;
    dst[(size_t)n * Kpad + k] = f2bf(tile[tx][ty + i]);
  }
}

// ---- features -> X' rows: [conts 13 | 0 | cate flat 1664 | pairs 741 | 0]
__global__ __launch_bounds__(256) void feature_kernel(
    const float* __restrict__ conts, const int* __restrict__ cates,
    const float* __restrict__ emb, unsigned short* __restrict__ X) {
  __shared__ unsigned short cc[4][48 * CCLD];
  __shared__ unsigned short pb[4][752];
  int wid = threadIdx.x >> 6, lane = threadIdx.x & 63;
  int b = (blockIdx.x << 2) | wid;
  unsigned short* my = cc[wid];
  unsigned short* pw = pb[wid];
  unsigned short* Xrow = X + (size_t)b * KX;

#pragma unroll
  for (int f = 0; f < 13; ++f)
    my[f * CCLD + lane] = f2bf(emb[f * 64 + lane] * conts[b * 13 + f]);
#pragma unroll 2
  for (int j = 0; j < 26; ++j) {
    int idx = cates[b * 26 + j];
    my[(13 + j) * CCLD + lane] = f2bf(emb[(size_t)idx * 64 + lane]);
  }
#pragma unroll
  for (int f = NF; f < 48; ++f) my[f * CCLD + lane] = 0;
  if (lane < 16) Xrow[lane] = (lane < 13) ? f2bf(conts[b * 13 + lane]) : 0;
  if (lane < 752 - NPAIR) pw[NPAIR + lane] = 0;
  __syncthreads();

  // cate flat: 1664 shorts = 208 x bf16x8
#pragma unroll
  for (int i = 0; i < 4; ++i) {
    int q = i * 64 + lane;
    if (q < 208)
      *(bf16x8*)&Xrow[16 + q * 8] =
          *(const bf16x8*)&my[(13 + (q >> 3)) * CCLD + (q & 7) * 8];
  }

  // gram via MFMA (frag is both A and B operand)
  int r15 = lane & 15, hi = lane >> 4;
  bf16x8 fr[2][3];
#pragma unroll
  for (int t = 0; t < 3; ++t)
#pragma unroll
    for (int h = 0; h < 2; ++h)
      fr[h][t] = *(const bf16x8*)&my[(t * 16 + r15) * CCLD + h * 32 + hi * 8];

  f32x4 acc[3][3];
#pragma unroll
  for (int it = 0; it < 3; ++it)
#pragma unroll
    for (int jt = 0; jt < 3; ++jt)
      acc[it][jt] = (f32x4){0.f, 0.f, 0.f, 0.f};
#pragma unroll
  for (int h = 0; h < 2; ++h)
#pragma unroll
    for (int it = 0; it < 3; ++it)
#pragma unroll
      for (int jt = 0; jt < 3; ++jt)
        acc[it][jt] = __builtin_amdgcn_mfma_f32_16x16x32_bf16(
            fr[h][it], fr[h][jt], acc[it][jt], 0, 0, 0);

#pragma unroll
  for (int it = 0; it < 3; ++it)
#pragma unroll
    for (int jt = 0; jt < 3; ++jt) {
      int g = jt * 16 + r15;
#pragma unroll
      for (int r = 0; r < 4; ++r) {
        int f = it * 16 + hi * 4 + r;
        if (f < g && g < NF) {
          int p = f * 38 - ((f * (f - 1)) >> 1) + g - f - 1;
          pw[p] = f2bf(acc[it][jt][r]);
        }
      }
    }
  __syncthreads();

#pragma unroll
  for (int i = 0; i < 2; ++i) {
    int q = i * 64 + lane;
    if (q < 94)
      *(bf16x8*)&Xrow[1680 + q * 8] = *(const bf16x8*)&pw[q * 8];
  }
}

// ===================== 256x256 8-phase GEMM, read-ahead pipelined (race-fixed) ==========
// Region p issues ds_reads for MFMA(p+1) into a spare register bank; MFMA(p) waits a
// counted lgkmcnt. RACE FIX vs r4: the A(T+1) reads in region 2 now sit AFTER
// {vmcnt(2); s_barrier} so ALL waves' global_load_lds writes for A(T+1)/B(T+1) have
// landed before any wave reads them (vmcnt is wave-local; the barrier globalizes it).
// Region-3 B01(T+1) reads were already safe (they follow that same barrier).

#define GLL(s_, d_) __builtin_amdgcn_global_load_lds((gptr_t)(s_), (lptr_t)(d_), 16, 0, 0)
#define RD(p_) (*(const bf16x8*)(p_))
#define DSTA(buf, h) (lds + (buf) * 32768 + (h) * 8192 + sd)
#define DSTB(buf, h) (lds + (buf) * 32768 + 16384 + (h) * 8192 + sd)
#define STG(dst, srcb, tau) do { \
    const unsigned short* _s = (srcb) + (size_t)(tau) * 64; \
    GLL(_s, dst); GLL(_s + (size_t)64 * K, (dst) + 4096); } while (0)

#define PH_BAR(Nlit) do { \
    __builtin_amdgcn_s_barrier(); \
    asm volatile("s_waitcnt lgkmcnt(" #Nlit ")" ::: "memory"); \
    __builtin_amdgcn_sched_barrier(0); \
    __builtin_amdgcn_s_setprio(1); } while (0)
#define PH_END() do { \
    __builtin_amdgcn_s_setprio(0); \
    __builtin_amdgcn_s_barrier(); \
    __builtin_amdgcn_sched_barrier(0); } while (0)

#define MQ(I0, J0, AB, BB) do { \
    _Pragma("unroll") \
    for (int i_ = 0; i_ < 4; ++i_) \
      _Pragma("unroll") \
      for (int j_ = 0; j_ < 2; ++j_) { \
        acc[(I0) + i_][(J0) + j_] = __builtin_amdgcn_mfma_f32_16x16x32_bf16( \
            AB[i_][0], BB[j_][0], acc[(I0) + i_][(J0) + j_], 0, 0, 0); \
        acc[(I0) + i_][(J0) + j_] = __builtin_amdgcn_mfma_f32_16x16x32_bf16( \
            AB[i_][1], BB[j_][1], acc[(I0) + i_][(J0) + j_], 0, 0, 0); \
      } } while (0)

#define TILE_BODY(T_, CUR_, B01_, B23_) do { \
    const int nxt_ = (CUR_) ^ 1; \
    int ta_ = ((T_) + 1 < NT) ? (T_) + 1 : NT - 1; \
    int tb_ = ((T_) + 2 < NT) ? (T_) + 2 : NT - 1; \
    const unsigned short* aBc_ = aH + (CUR_) * 32768; \
    const unsigned short* aBn_ = aH + nxt_ * 32768; \
    const unsigned short* bBc_ = bH + (CUR_) * 32768; \
    const unsigned short* bBn_ = bH + nxt_ * 32768; \
    /* region 0: rd B23(T); STG A0(T+1); MFMA m0-3 x n0-1 */ \
    _Pragma("unroll") \
    for (int j_ = 0; j_ < 2; ++j_) { \
      B23_[j_][0] = RD(bBc_ + (2 + j_) * 1024 + rb0); \
      B23_[j_][1] = RD(bBc_ + (2 + j_) * 1024 + rb1); } \
    STG(DSTA(nxt_, 0), A0p, ta_); \
    PH_BAR(4); \
    MQ(0, 0, a0, B01_); \
    PH_END(); \
    /* region 1: rd A4-7(T) -> a1; STG A1(T+1); MFMA m0-3 x n2-3 */ \
    _Pragma("unroll") \
    for (int i_ = 0; i_ < 4; ++i_) { \
      a1[i_][0] = RD(aBc_ + (4 + i_) * 1024 + rb0); \
      a1[i_][1] = RD(aBc_ + (4 + i_) * 1024 + rb1); } \
    STG(DSTA(nxt_, 1), A1p, ta_); \
    PH_BAR(8); \
    MQ(0, 2, a0, B23_); \
    PH_END(); \
    /* region 2: STG B0(T+2); vmcnt(2); BARRIER; then rd A0-3(T+1) -> a0 (safe: */ \
    /* all waves drained their A(T+1)/B(T+1) GLLs before the barrier); MFMA m4-7 x n2-3 */ \
    STG(DSTB(CUR_, 0), B0p, tb_); \
    asm volatile("s_waitcnt vmcnt(2)" ::: "memory"); \
    asm volatile("s_barrier" ::: "memory"); \
    _Pragma("unroll") \
    for (int i_ = 0; i_ < 4; ++i_) { \
      a0[i_][0] = RD(aBn_ + i_ * 1024 + rb0); \
      a0[i_][1] = RD(aBn_ + i_ * 1024 + rb1); } \
    asm volatile("s_waitcnt lgkmcnt(8)" ::: "memory"); \
    __builtin_amdgcn_sched_barrier(0); \
    __builtin_amdgcn_s_setprio(1); \
    MQ(4, 2, a1, B23_); \
    PH_END(); \
    /* region 3: STG B1(T+2); rd B0-1(T+1) -> B23_ (B(T+1) landed per region-2 barrier); */ \
    /* MFMA m4-7 x n0-1 (operands a1/B01_ already forced complete) */ \
    STG(DSTB(CUR_, 1), B1p, tb_); \
    _Pragma("unroll") \
    for (int j_ = 0; j_ < 2; ++j_) { \
      B23_[j_][0] = RD(bBn_ + j_ * 1024 + rb0); \
      B23_[j_][1] = RD(bBn_ + j_ * 1024 + rb1); } \
    PH_BAR(12); \
    MQ(4, 0, a1, B01_); \
    PH_END(); \
  } while (0)

__global__ __launch_bounds__(512, 2) void gemm_8ph(
    const unsigned short* __restrict__ A, const unsigned short* __restrict__ Bt,
    const float* __restrict__ bias, unsigned short* __restrict__ Hout,
    int K, int NT) {
  __shared__ unsigned short lds[65536];  // 128 KiB

  int bid = blockIdx.x;
  int swz = (bid & 7) * 32 + (bid >> 3);  // 256 wgs, 8 XCDs, chunked (bijective)
  int mb = swz >> 2, nb = swz & 3;
  size_t m0 = (size_t)mb * 256, n0 = (size_t)nb * 256;

  int tid = threadIdx.x, lane = tid & 63, w = tid >> 6;
  int wr = w >> 2, wc = w & 3;
  int r15 = lane & 15, hi = lane >> 4;

  int sr = tid >> 3;
  int ce = ((tid & 7) ^ (sr & 7)) << 3;   // inverse-swizzled global col group
  int sd = tid * 8;                        // linear LDS dest (shorts)
  const unsigned short* A0p = A + (m0 + sr) * (size_t)K + ce;
  const unsigned short* A1p = A0p + (size_t)128 * K;
  const unsigned short* B0p = Bt + (n0 + sr) * (size_t)K + ce;
  const unsigned short* B1p = B0p + (size_t)128 * K;

  int cbs = (((hi << 4) ^ ((r15 & 7) << 4)) >> 1);  // swizzled read col (shorts)
  int rb0 = r15 * 64 + cbs;
  int rb1 = rb0 ^ 32;
  const unsigned short* aH = lds + wr * 8192;
  const unsigned short* bH = lds + 16384 + (wc >> 1) * 8192 + (wc & 1) * 4096;

  f32x4 acc[8][4];
#pragma unroll
  for (int m = 0; m < 8; ++m)
#pragma unroll
    for (int n = 0; n < 4; ++n) acc[m][n] = (f32x4){0.f, 0.f, 0.f, 0.f};

  bf16x8 a0[4][2], a1[4][2], bP[2][2], bQ[2][2];

  // ---- prologue: stage A(0),B(0); drain ALL; barrier; stage B(1); pre-read tile0 frags
  {
    int t1 = (NT > 1) ? 1 : 0;
    STG(DSTB(0, 0), B0p, 0);
    STG(DSTB(0, 1), B1p, 0);
    STG(DSTA(0, 0), A0p, 0);
    STG(DSTA(0, 1), A1p, 0);
    asm volatile("s_waitcnt vmcnt(0)" ::: "memory");
    __builtin_amdgcn_s_barrier();
    __builtin_amdgcn_sched_barrier(0);
    STG(DSTB(1, 0), B0p, t1);
    STG(DSTB(1, 1), B1p, t1);
#pragma unroll
    for (int i = 0; i < 4; ++i) {
      a0[i][0] = RD(aH + i * 1024 + rb0);
      a0[i][1] = RD(aH + i * 1024 + rb1);
    }
#pragma unroll
    for (int j = 0; j < 2; ++j) {
      bP[j][0] = RD(bH + j * 1024 + rb0);
      bP[j][1] = RD(bH + j * 1024 + rb1);
    }
  }

  for (int t = 0; t < NT; t += 2) {   // NT even
    TILE_BODY(t, 0, bP, bQ);
    TILE_BODY(t + 1, 1, bQ, bP);
  }

  // epilogue: +bias, bf16 store. C/D: col=lane&15, row=(lane>>4)*4+q
  size_t crow = m0 + (size_t)wr * 128 + hi * 4;
  size_t ccol = n0 + (size_t)wc * 64 + r15;
  unsigned short* Hp = Hout + crow * NH + ccol;
  float bv[4];
#pragma unroll
  for (int n = 0; n < 4; ++n) bv[n] = bias[ccol + n * 16];
#pragma unroll
  for (int m = 0; m < 8; ++m)
#pragma unroll
    for (int n = 0; n < 4; ++n)
#pragma unroll
      for (int q = 0; q < 4; ++q)
        Hp[(size_t)(m * 16 + q) * NH + n * 16] = f2bf(acc[m][n][q] + bv[n]);
}

// ---- layernorm + relu (bf16 in -> bf16 out), one block per row
__global__ __launch_bounds__(256) void ln_relu_kernel(
    const unsigned short* __restrict__ Yb, const float* __restrict__ gamma,
    const float* __restrict__ beta, unsigned short* __restrict__ H) {
  int b = blockIdx.x, tid = threadIdx.x;
  ushort4 u = ((const ushort4*)(Yb + (size_t)b * NH))[tid];
  float v0 = bf2f(u.x), v1 = bf2f(u.y), v2 = bf2f(u.z), v3 = bf2f(u.w);
  float s1 = v0 + v1 + v2 + v3;
  float s2 = v0 * v0 + v1 * v1 + v2 * v2 + v3 * v3;
#pragma unroll
  for (int i = 1; i < 64; i <<= 1) {
    s1 += __shfl_xor(s1, i);
    s2 += __shfl_xor(s2, i);
  }
  __shared__ float a1[4], a2[4];
  int wid = tid >> 6, lane = tid & 63;
  if (lane == 0) { a1[wid] = s1; a2[wid] = s2; }
  __syncthreads();
  s1 = a1[0] + a1[1] + a1[2] + a1[3];
  s2 = a2[0] + a2[1] + a2[2] + a2[3];
  float mu = s1 * (1.0f / NH);
  float var = s2 * (1.0f / NH) - mu * mu;
  float rs = rsqrtf(var + 1e-5f);
  float4 gg = ((const float4*)gamma)[tid];
  float4 be = ((const float4*)beta)[tid];
  ushort4 wv;
  wv.x = f2bf(fmaxf((v0 - mu) * rs * gg.x + be.x, 0.f));
  wv.y = f2bf(fmaxf((v1 - mu) * rs * gg.y + be.y, 0.f));
  wv.z = f2bf(fmaxf((v2 - mu) * rs * gg.z + be.z, 0.f));
  wv.w = f2bf(fmaxf((v3 - mu) * rs * gg.w + be.w, 0.f));
  ((ushort4*)(H + (size_t)b * NH))[tid] = wv;
}

// ---- layernorm + relu + dot(Wout) + sigmoid, one block per row
__global__ __launch_bounds__(256) void ln_out_kernel(
    const unsigned short* __restrict__ Yb, const float* __restrict__ gamma,
    const float* __restrict__ beta, const float* __restrict__ Wout,
    const float* __restrict__ bout, float* __restrict__ out) {
  int b = blockIdx.x, tid = threadIdx.x;
  ushort4 u = ((const ushort4*)(Yb + (size_t)b * NH))[tid];
  float v0 = bf2f(u.x), v1 = bf2f(u.y), v2 = bf2f(u.z), v3 = bf2f(u.w);
  float s1 = v0 + v1 + v2 + v3;
  float s2 = v0 * v0 + v1 * v1 + v2 * v2 + v3 * v3;
#pragma unroll
  for (int i = 1; i < 64; i <<= 1) {
    s1 += __shfl_xor(s1, i);
    s2 += __shfl_xor(s2, i);
  }
  __shared__ float a1[4], a2[4], a3[4];
  int wid = tid >> 6, lane = tid & 63;
  if (lane == 0) { a1[wid] = s1; a2[wid] = s2; }
  __syncthreads();
  s1 = a1[0] + a1[1] + a1[2] + a1[3];
  s2 = a2[0] + a2[1] + a2[2] + a2[3];
  float mu = s1 * (1.0f / NH);
  float var = s2 * (1.0f / NH) - mu * mu;
  float rs = rsqrtf(var + 1e-5f);
  float4 gg = ((const float4*)gamma)[tid];
  float4 be = ((const float4*)beta)[tid];
  float o0 = fmaxf((v0 - mu) * rs * gg.x + be.x, 0.f);
  float o1 = fmaxf((v1 - mu) * rs * gg.y + be.y, 0.f);
  float o2 = fmaxf((v2 - mu) * rs * gg.z + be.z, 0.f);
  float o3 = fmaxf((v3 - mu) * rs * gg.w + be.w, 0.f);
  float4 wo = ((const float4*)Wout)[tid];
  float s = o0 * wo.x + o1 * wo.y + o2 * wo.z + o3 * wo.w;
#pragma unroll
  for (int i = 1; i < 64; i <<= 1) s += __shfl_xor(s, i);
  if (lane == 0) a3[wid] = s;
  __syncthreads();
  if (tid == 0) {
    float tot = a3[0] + a3[1] + a3[2] + a3[3];
    out[b] = 1.f / (1.f + expf(-(tot + bout[0])));
  }
}

extern "C" void kernel_launch(void* const* d_in, const int* in_sizes, int n_in,
                              void* d_out, int out_size, void* d_ws, size_t ws_size,
                              hipStream_t stream) {
  const float* conts = (const float*)d_in[0];
  const int* cates = (const int*)d_in[1];
  const float* emb  = (const float*)d_in[3];
  const float* W1   = (const float*)d_in[4];
  const float* b1   = (const float*)d_in[5];
  const float* ln1g = (const float*)d_in[6];
  const float* ln1b = (const float*)d_in[7];
  const float* W2   = (const float*)d_in[8];
  const float* b2   = (const float*)d_in[9];
  const float* ln2g = (const float*)d_in[10];
  const float* ln2b = (const float*)d_in[11];
  const float* Wout = (const float*)d_in[12];
  const float* bout = (const float*)d_in[13];
  float* out = (float*)d_out;

  unsigned short* X   = (unsigned short*)d_ws;            // BATCH * KX
  unsigned short* W1t = X + (size_t)BATCH * KX;           // NH * KX
  unsigned short* W2t = W1t + (size_t)NH * KX;            // NH * NH
  unsigned short* H1  = W2t + (size_t)NH * NH;            // BATCH * NH
  unsigned short* Yb1 = H1 + (size_t)BATCH * NH;          // BATCH * NH
  unsigned short* Yb2 = Yb1 + (size_t)BATCH * NH;         // BATCH * NH

  hipLaunchKernelGGL(build_w1t_kernel, dim3(KX / 32, NH / 32), dim3(256), 0, stream,
                     W1, emb, W1t);
  hipLaunchKernelGGL(transpose_cast_kernel, dim3(NH / 32, NH / 32), dim3(256), 0, stream,
                     W2, W2t, NH, NH, NH);
  hipLaunchKernelGGL(feature_kernel, dim3(BATCH / 4), dim3(256), 0, stream,
                     conts, cates, emb, X);
  hipLaunchKernelGGL(gemm_8ph, dim3(256), dim3(512), 0, stream,
                     X, W1t, b1, Yb1, KX, KX / 64);
  hipLaunchKernelGGL(ln_relu_kernel, dim3(BATCH), dim3(256), 0, stream,
                     Yb1, ln1g, ln1b, H1);
  hipLaunchKernelGGL(gemm_8ph, dim3(256), dim3(512), 0, stream,
                     H1, W2t, b2, Yb2, NH, NH / 64);
  hipLaunchKernelGGL(ln_out_kernel, dim3(BATCH), dim3(256), 0, stream,
                     Yb2, ln2g, ln2b, Wout, bout, out);
}

// Round 6
// 194.084 us; speedup vs baseline: 1.1578x; 1.1578x over previous
//
#include <hip/hip_runtime.h>
#include <hip/hip_bf16.h>

#define BATCH 16384
#define NH 1024
#define NF 39
#define CCLD 72
#define KX 2432      // GEMM1 K: [0:13 conts][13:16 pad0][16:1680 cate flat][1680:2421 pairs][2421:2432 pad0]
#define NPAIR 741

typedef __attribute__((ext_vector_type(8))) short bf16x8;
typedef __attribute__((ext_vector_type(4))) float f32x4;

typedef const __attribute__((address_space(1))) unsigned int* gptr_t;
typedef __attribute__((address_space(3))) unsigned int* lptr_t;

__device__ __forceinline__ float bf2f(unsigned short u) {
  union { unsigned int i; float f; } c; c.i = ((unsigned int)u) << 16; return c.f;
}
__device__ __forceinline__ unsigned short f2bf(float f) {
  union { float f; unsigned int i; } c; c.f = f;
  unsigned int r = c.i + 0x7FFFu + ((c.i >> 16) & 1u);
  return (unsigned short)(r >> 16);
}

// ---- merged W-prep: blocks [0,76) build W1t (row-remapped, M13 inline), [76,108) build W2t
__global__ __launch_bounds__(256) void wprep_kernel(
    const float* __restrict__ W1, const float* __restrict__ W2,
    const float* __restrict__ emb, unsigned short* __restrict__ W1t,
    unsigned short* __restrict__ W2t) {
  __shared__ float tile[32][33];
  int bx = blockIdx.x;
  int nb = blockIdx.y * 32;
  int tx = threadIdx.x & 31, ty = threadIdx.x >> 5;
  if (bx < KX / 32) {
    int kb = bx * 32;
#pragma unroll
    for (int i = 0; i < 32; i += 8) {
      int k = kb + ty + i;
      float v = 0.f;
      if (k < 13) {
        float s = 0.f;
#pragma unroll 8
        for (int d = 0; d < 64; ++d)
          s += emb[k * 64 + d] * W1[(size_t)(k * 64 + d) * NH + nb + tx];
        v = s;
      } else if (k >= 16 && k < 1680) {
        v = W1[(size_t)(832 + k - 16) * NH + nb + tx];
      } else if (k >= 1680 && k < 1680 + NPAIR) {
        v = W1[(size_t)(2496 + k - 1680) * NH + nb + tx];
      }
      tile[ty + i][tx] = v;
    }
    __syncthreads();
#pragma unroll
    for (int i = 0; i < 32; i += 8)
      W1t[(size_t)(nb + ty + i) * KX + kb + tx] = f2bf(tile[tx][ty + i]);
  } else {
    int kb = (bx - KX / 32) * 32;
#pragma unroll
    for (int i = 0; i < 32; i += 8)
      tile[ty + i][tx] = W2[(size_t)(kb + ty + i) * NH + nb + tx];
    __syncthreads();
#pragma unroll
    for (int i = 0; i < 32; i += 8)
      W2t[(size_t)(nb + ty + i) * NH + kb + tx] = f2bf(tile[tx][ty + i]);
  }
}

// ---- features -> X' rows: [conts 13 | 0 | cate flat 1664 | pairs 741 | 0]
__global__ __launch_bounds__(256) void feature_kernel(
    const float* __restrict__ conts, const int* __restrict__ cates,
    const float* __restrict__ emb, unsigned short* __restrict__ X) {
  __shared__ unsigned short cc[4][48 * CCLD];
  __shared__ unsigned short pb[4][752];
  int wid = threadIdx.x >> 6, lane = threadIdx.x & 63;
  int b = (blockIdx.x << 2) | wid;
  unsigned short* my = cc[wid];
  unsigned short* pw = pb[wid];
  unsigned short* Xrow = X + (size_t)b * KX;

#pragma unroll
  for (int f = 0; f < 13; ++f)
    my[f * CCLD + lane] = f2bf(emb[f * 64 + lane] * conts[b * 13 + f]);
#pragma unroll 2
  for (int j = 0; j < 26; ++j) {
    int idx = cates[b * 26 + j];
    my[(13 + j) * CCLD + lane] = f2bf(emb[(size_t)idx * 64 + lane]);
  }
#pragma unroll
  for (int f = NF; f < 48; ++f) my[f * CCLD + lane] = 0;
  if (lane < 16) Xrow[lane] = (lane < 13) ? f2bf(conts[b * 13 + lane]) : 0;
  if (lane < 752 - NPAIR) pw[NPAIR + lane] = 0;
  __syncthreads();

  // cate flat: 1664 shorts = 208 x bf16x8
#pragma unroll
  for (int i = 0; i < 4; ++i) {
    int q = i * 64 + lane;
    if (q < 208)
      *(bf16x8*)&Xrow[16 + q * 8] =
          *(const bf16x8*)&my[(13 + (q >> 3)) * CCLD + (q & 7) * 8];
  }

  // gram via MFMA (frag is both A and B operand)
  int r15 = lane & 15, hi = lane >> 4;
  bf16x8 fr[2][3];
#pragma unroll
  for (int t = 0; t < 3; ++t)
#pragma unroll
    for (int h = 0; h < 2; ++h)
      fr[h][t] = *(const bf16x8*)&my[(t * 16 + r15) * CCLD + h * 32 + hi * 8];

  f32x4 acc[3][3];
#pragma unroll
  for (int it = 0; it < 3; ++it)
#pragma unroll
    for (int jt = 0; jt < 3; ++jt)
      acc[it][jt] = (f32x4){0.f, 0.f, 0.f, 0.f};
#pragma unroll
  for (int h = 0; h < 2; ++h)
#pragma unroll
    for (int it = 0; it < 3; ++it)
#pragma unroll
      for (int jt = 0; jt < 3; ++jt)
        acc[it][jt] = __builtin_amdgcn_mfma_f32_16x16x32_bf16(
            fr[h][it], fr[h][jt], acc[it][jt], 0, 0, 0);

#pragma unroll
  for (int it = 0; it < 3; ++it)
#pragma unroll
    for (int jt = 0; jt < 3; ++jt) {
      int g = jt * 16 + r15;
#pragma unroll
      for (int r = 0; r < 4; ++r) {
        int f = it * 16 + hi * 4 + r;
        if (f < g && g < NF) {
          int p = f * 38 - ((f * (f - 1)) >> 1) + g - f - 1;
          pw[p] = f2bf(acc[it][jt][r]);
        }
      }
    }
  __syncthreads();

#pragma unroll
  for (int i = 0; i < 2; ++i) {
    int q = i * 64 + lane;
    if (q < 94)
      *(bf16x8*)&Xrow[1680 + q * 8] = *(const bf16x8*)&pw[q * 8];
  }
}

// ===================== 256x256 8-phase GEMM (r3 schedule, verbatim) =====================
// Hout(M x 1024 bf16) = A(M x K bf16) * Bt(1024 x K bf16)^T + bias. K mult of 64.

#define GLL(s_, d_) __builtin_amdgcn_global_load_lds((gptr_t)(s_), (lptr_t)(d_), 16, 0, 0)
#define RD(p_) (*(const bf16x8*)(p_))
#define DSTA(buf, h) (lds + (buf) * 32768 + (h) * 8192 + sd)
#define DSTB(buf, h) (lds + (buf) * 32768 + 16384 + (h) * 8192 + sd)
#define STG(dst, srcb, tau) do { \
    const unsigned short* _s = (srcb) + (size_t)(tau) * 64; \
    GLL(_s, dst); GLL(_s + (size_t)64 * K, (dst) + 4096); } while (0)
#define PHASE_BAR() do { \
    __builtin_amdgcn_s_barrier(); \
    asm volatile("s_waitcnt lgkmcnt(0)" ::: "memory"); \
    __builtin_amdgcn_sched_barrier(0); \
    __builtin_amdgcn_s_setprio(1); } while (0)
#define PHASE_END() do { \
    __builtin_amdgcn_s_setprio(0); \
    __builtin_amdgcn_s_barrier(); \
    __builtin_amdgcn_sched_barrier(0); } while (0)

__global__ __launch_bounds__(512, 2) void gemm_8ph(
    const unsigned short* __restrict__ A, const unsigned short* __restrict__ Bt,
    const float* __restrict__ bias, unsigned short* __restrict__ Hout,
    int K, int NT) {
  __shared__ unsigned short lds[65536];  // 128 KiB

  int bid = blockIdx.x;
  int swz = (bid & 7) * 32 + (bid >> 3);  // 256 wgs, 8 XCDs, chunked (bijective)
  int mb = swz >> 2, nb = swz & 3;
  size_t m0 = (size_t)mb * 256, n0 = (size_t)nb * 256;

  int tid = threadIdx.x, lane = tid & 63, w = tid >> 6;
  int wr = w >> 2, wc = w & 3;
  int r15 = lane & 15, hi = lane >> 4;

  int sr = tid >> 3;
  int ce = ((tid & 7) ^ (sr & 7)) << 3;   // inverse-swizzled global col group
  int sd = tid * 8;                        // linear LDS dest (shorts)
  const unsigned short* A0p = A + (m0 + sr) * (size_t)K + ce;
  const unsigned short* A1p = A0p + (size_t)128 * K;
  const unsigned short* B0p = Bt + (n0 + sr) * (size_t)K + ce;
  const unsigned short* B1p = B0p + (size_t)128 * K;

  int cbs = (((hi << 4) ^ ((r15 & 7) << 4)) >> 1);  // swizzled read col (shorts)
  int rb0 = r15 * 64 + cbs;
  int rb1 = rb0 ^ 32;
  const unsigned short* aH = lds + wr * 8192;
  const unsigned short* bH = lds + 16384 + (wc >> 1) * 8192 + (wc & 1) * 4096;

  f32x4 acc[8][4];
#pragma unroll
  for (int m = 0; m < 8; ++m)
#pragma unroll
    for (int n = 0; n < 4; ++n) acc[m][n] = (f32x4){0.f, 0.f, 0.f, 0.f};

  {
    int t1 = (NT > 1) ? 1 : 0;
    STG(DSTB(0, 0), B0p, 0);
    STG(DSTB(0, 1), B1p, 0);
    STG(DSTA(0, 0), A0p, 0);
    STG(DSTA(0, 1), A1p, 0);
    STG(DSTB(1, 0), B0p, t1);
    STG(DSTB(1, 1), B1p, t1);
    asm volatile("s_waitcnt vmcnt(4)" ::: "memory");
    __builtin_amdgcn_s_barrier();
    __builtin_amdgcn_sched_barrier(0);
  }

  bf16x8 aF[4][2], bF[4][2];

  for (int t = 0; t < NT; ++t) {
    int cur = t & 1, nxt = cur ^ 1;
    int ta = (t + 1 < NT) ? t + 1 : NT - 1;  // clamped dummies stay in-bounds
    int tb = (t + 2 < NT) ? t + 2 : NT - 1;
    const unsigned short* aB = aH + cur * 32768;
    const unsigned short* bB = bH + cur * 32768;

    // phase 0: read A0-3,B0-1; stage A-half0(t+1); MFMA (m0-3, n0-1)
#pragma unroll
    for (int i = 0; i < 4; ++i) {
      aF[i][0] = RD(aB + i * 1024 + rb0);
      aF[i][1] = RD(aB + i * 1024 + rb1);
    }
#pragma unroll
    for (int j = 0; j < 2; ++j) {
      bF[j][0] = RD(bB + j * 1024 + rb0);
      bF[j][1] = RD(bB + j * 1024 + rb1);
    }
    STG(DSTA(nxt, 0), A0p, ta);
    PHASE_BAR();
#pragma unroll
    for (int i = 0; i < 4; ++i)
#pragma unroll
      for (int j = 0; j < 2; ++j) {
        acc[i][j] = __builtin_amdgcn_mfma_f32_16x16x32_bf16(aF[i][0], bF[j][0], acc[i][j], 0, 0, 0);
        acc[i][j] = __builtin_amdgcn_mfma_f32_16x16x32_bf16(aF[i][1], bF[j][1], acc[i][j], 0, 0, 0);
      }
    PHASE_END();

    // phase 1: read B2-3; stage A-half1(t+1); MFMA (m0-3, n2-3)
#pragma unroll
    for (int j = 0; j < 2; ++j) {
      bF[2 + j][0] = RD(bB + (2 + j) * 1024 + rb0);
      bF[2 + j][1] = RD(bB + (2 + j) * 1024 + rb1);
    }
    STG(DSTA(nxt, 1), A1p, ta);
    PHASE_BAR();
#pragma unroll
    for (int i = 0; i < 4; ++i)
#pragma unroll
      for (int j = 0; j < 2; ++j) {
        acc[i][2 + j] = __builtin_amdgcn_mfma_f32_16x16x32_bf16(aF[i][0], bF[2 + j][0], acc[i][2 + j], 0, 0, 0);
        acc[i][2 + j] = __builtin_amdgcn_mfma_f32_16x16x32_bf16(aF[i][1], bF[2 + j][1], acc[i][2 + j], 0, 0, 0);
      }
    PHASE_END();

    // phase 2: read A4-7; stage B-half0(t+2); MFMA (m4-7, n2-3)
#pragma unroll
    for (int i = 0; i < 4; ++i) {
      aF[i][0] = RD(aB + (4 + i) * 1024 + rb0);
      aF[i][1] = RD(aB + (4 + i) * 1024 + rb1);
    }
    STG(DSTB(cur, 0), B0p, tb);
    PHASE_BAR();
#pragma unroll
    for (int i = 0; i < 4; ++i)
#pragma unroll
      for (int j = 0; j < 2; ++j) {
        acc[4 + i][2 + j] = __builtin_amdgcn_mfma_f32_16x16x32_bf16(aF[i][0], bF[2 + j][0], acc[4 + i][2 + j], 0, 0, 0);
        acc[4 + i][2 + j] = __builtin_amdgcn_mfma_f32_16x16x32_bf16(aF[i][1], bF[2 + j][1], acc[4 + i][2 + j], 0, 0, 0);
      }
    PHASE_END();

    // phase 3: stage B-half1(t+2); vmcnt(4); MFMA (m4-7, n0-1)
    STG(DSTB(cur, 1), B1p, tb);
    asm volatile("s_waitcnt vmcnt(4)" ::: "memory");
    PHASE_BAR();
#pragma unroll
    for (int i = 0; i < 4; ++i)
#pragma unroll
      for (int j = 0; j < 2; ++j) {
        acc[4 + i][j] = __builtin_amdgcn_mfma_f32_16x16x32_bf16(aF[i][0], bF[j][0], acc[4 + i][j], 0, 0, 0);
        acc[4 + i][j] = __builtin_amdgcn_mfma_f32_16x16x32_bf16(aF[i][1], bF[j][1], acc[4 + i][j], 0, 0, 0);
      }
    PHASE_END();
  }

  // epilogue: +bias, bf16 store. C/D: col=lane&15, row=(lane>>4)*4+q
  size_t crow = m0 + (size_t)wr * 128 + hi * 4;
  size_t ccol = n0 + (size_t)wc * 64 + r15;
  unsigned short* Hp = Hout + crow * NH + ccol;
  float bv[4];
#pragma unroll
  for (int n = 0; n < 4; ++n) bv[n] = bias[ccol + n * 16];
#pragma unroll
  for (int m = 0; m < 8; ++m)
#pragma unroll
    for (int n = 0; n < 4; ++n)
#pragma unroll
      for (int q = 0; q < 4; ++q)
        Hp[(size_t)(m * 16 + q) * NH + n * 16] = f2bf(acc[m][n][q] + bv[n]);
}

// ---- layernorm + relu, wave-per-row (16 elems/lane), no LDS / no block sync
__global__ __launch_bounds__(256) void ln_relu_kernel(
    const unsigned short* __restrict__ Yb, const float* __restrict__ gamma,
    const float* __restrict__ beta, unsigned short* __restrict__ H) {
  int wid = threadIdx.x >> 6, lane = threadIdx.x & 63;
  int b = (blockIdx.x << 2) | wid;
  const unsigned short* yrow = Yb + (size_t)b * NH + lane * 16;
  bf16x8 u0 = *(const bf16x8*)&yrow[0];
  bf16x8 u1 = *(const bf16x8*)&yrow[8];
  float v[16];
#pragma unroll
  for (int i = 0; i < 8; ++i) {
    v[i] = bf2f((unsigned short)u0[i]);
    v[8 + i] = bf2f((unsigned short)u1[i]);
  }
  float s1 = 0.f, s2 = 0.f;
#pragma unroll
  for (int i = 0; i < 16; ++i) { s1 += v[i]; s2 += v[i] * v[i]; }
#pragma unroll
  for (int i = 1; i < 64; i <<= 1) {
    s1 += __shfl_xor(s1, i);
    s2 += __shfl_xor(s2, i);
  }
  float mu = s1 * (1.0f / NH);
  float var = s2 * (1.0f / NH) - mu * mu;
  float rs = rsqrtf(var + 1e-5f);
  const float4* gp = (const float4*)(gamma + lane * 16);
  const float4* bp = (const float4*)(beta + lane * 16);
  unsigned short o[16];
#pragma unroll
  for (int q = 0; q < 4; ++q) {
    float4 gg = gp[q], be = bp[q];
    o[q * 4 + 0] = f2bf(fmaxf((v[q * 4 + 0] - mu) * rs * gg.x + be.x, 0.f));
    o[q * 4 + 1] = f2bf(fmaxf((v[q * 4 + 1] - mu) * rs * gg.y + be.y, 0.f));
    o[q * 4 + 2] = f2bf(fmaxf((v[q * 4 + 2] - mu) * rs * gg.z + be.z, 0.f));
    o[q * 4 + 3] = f2bf(fmaxf((v[q * 4 + 3] - mu) * rs * gg.w + be.w, 0.f));
  }
  unsigned short* hrow = H + (size_t)b * NH + lane * 16;
  *(ulonglong2*)&hrow[0] = *(const ulonglong2*)&o[0];
  *(ulonglong2*)&hrow[8] = *(const ulonglong2*)&o[8];
}

// ---- layernorm + relu + dot(Wout) + sigmoid, wave-per-row
__global__ __launch_bounds__(256) void ln_out_kernel(
    const unsigned short* __restrict__ Yb, const float* __restrict__ gamma,
    const float* __restrict__ beta, const float* __restrict__ Wout,
    const float* __restrict__ bout, float* __restrict__ out) {
  int wid = threadIdx.x >> 6, lane = threadIdx.x & 63;
  int b = (blockIdx.x << 2) | wid;
  const unsigned short* yrow = Yb + (size_t)b * NH + lane * 16;
  bf16x8 u0 = *(const bf16x8*)&yrow[0];
  bf16x8 u1 = *(const bf16x8*)&yrow[8];
  float v[16];
#pragma unroll
  for (int i = 0; i < 8; ++i) {
    v[i] = bf2f((unsigned short)u0[i]);
    v[8 + i] = bf2f((unsigned short)u1[i]);
  }
  float s1 = 0.f, s2 = 0.f;
#pragma unroll
  for (int i = 0; i < 16; ++i) { s1 += v[i]; s2 += v[i] * v[i]; }
#pragma unroll
  for (int i = 1; i < 64; i <<= 1) {
    s1 += __shfl_xor(s1, i);
    s2 += __shfl_xor(s2, i);
  }
  float mu = s1 * (1.0f / NH);
  float var = s2 * (1.0f / NH) - mu * mu;
  float rs = rsqrtf(var + 1e-5f);
  const float4* gp = (const float4*)(gamma + lane * 16);
  const float4* bp = (const float4*)(beta + lane * 16);
  const float4* wp = (const float4*)(Wout + lane * 16);
  float s = 0.f;
#pragma unroll
  for (int q = 0; q < 4; ++q) {
    float4 gg = gp[q], be = bp[q], wo = wp[q];
    s += fmaxf((v[q * 4 + 0] - mu) * rs * gg.x + be.x, 0.f) * wo.x;
    s += fmaxf((v[q * 4 + 1] - mu) * rs * gg.y + be.y, 0.f) * wo.y;
    s += fmaxf((v[q * 4 + 2] - mu) * rs * gg.z + be.z, 0.f) * wo.z;
    s += fmaxf((v[q * 4 + 3] - mu) * rs * gg.w + be.w, 0.f) * wo.w;
  }
#pragma unroll
  for (int i = 1; i < 64; i <<= 1) s += __shfl_xor(s, i);
  if (lane == 0) out[b] = 1.f / (1.f + expf(-(s + bout[0])));
}

extern "C" void kernel_launch(void* const* d_in, const int* in_sizes, int n_in,
                              void* d_out, int out_size, void* d_ws, size_t ws_size,
                              hipStream_t stream) {
  const float* conts = (const float*)d_in[0];
  const int* cates = (const int*)d_in[1];
  const float* emb  = (const float*)d_in[3];
  const float* W1   = (const float*)d_in[4];
  const float* b1   = (const float*)d_in[5];
  const float* ln1g = (const float*)d_in[6];
  const float* ln1b = (const float*)d_in[7];
  const float* W2   = (const float*)d_in[8];
  const float* b2   = (const float*)d_in[9];
  const float* ln2g = (const float*)d_in[10];
  const float* ln2b = (const float*)d_in[11];
  const float* Wout = (const float*)d_in[12];
  const float* bout = (const float*)d_in[13];
  float* out = (float*)d_out;

  unsigned short* X   = (unsigned short*)d_ws;            // BATCH * KX
  unsigned short* W1t = X + (size_t)BATCH * KX;           // NH * KX
  unsigned short* W2t = W1t + (size_t)NH * KX;            // NH * NH
  unsigned short* H1  = W2t + (size_t)NH * NH;            // BATCH * NH
  unsigned short* Yb1 = H1 + (size_t)BATCH * NH;          // BATCH * NH
  unsigned short* Yb2 = Yb1 + (size_t)BATCH * NH;         // BATCH * NH

  hipLaunchKernelGGL(wprep_kernel, dim3(KX / 32 + NH / 32, NH / 32), dim3(256), 0, stream,
                     W1, W2, emb, W1t, W2t);
  hipLaunchKernelGGL(feature_kernel, dim3(BATCH / 4), dim3(256), 0, stream,
                     conts, cates, emb, X);
  hipLaunchKernelGGL(gemm_8ph, dim3(256), dim3(512), 0, stream,
                     X, W1t, b1, Yb1, KX, KX / 64);
  hipLaunchKernelGGL(ln_relu_kernel, dim3(BATCH / 4), dim3(256), 0, stream,
                     Yb1, ln1g, ln1b, H1);
  hipLaunchKernelGGL(gemm_8ph, dim3(256), dim3(512), 0, stream,
                     H1, W2t, b2, Yb2, NH, NH / 64);
  hipLaunchKernelGGL(ln_out_kernel, dim3(BATCH / 4), dim3(256), 0, stream,
                     Yb2, ln2g, ln2b, Wout, bout, out);
}

// Round 7
// 193.955 us; speedup vs baseline: 1.1586x; 1.0007x over previous
//
#include <hip/hip_runtime.h>
#include <hip/hip_bf16.h>

#define BATCH 16384
#define NH 1024
#define NF 39
#define CCLD 72
#define KX 2432      // GEMM1 K: [0:13 conts][13:16 pad0][16:1680 cate flat][1680:2421 pairs][2421:2432 pad0]
#define NPAIR 741

typedef __attribute__((ext_vector_type(8))) short bf16x8;
typedef __attribute__((ext_vector_type(4))) float f32x4;

typedef const __attribute__((address_space(1))) unsigned int* gptr_t;
typedef __attribute__((address_space(3))) unsigned int* lptr_t;

__device__ __forceinline__ float bf2f(unsigned short u) {
  union { unsigned int i; float f; } c; c.i = ((unsigned int)u) << 16; return c.f;
}
__device__ __forceinline__ unsigned short f2bf(float f) {
  union { float f; unsigned int i; } c; c.f = f;
  unsigned int r = c.i + 0x7FFFu + ((c.i >> 16) & 1u);
  return (unsigned short)(r >> 16);
}

// ---- merged W-prep: blocks [0,76) build W1t (row-remapped, M13 inline), [76,108) build W2t
__global__ __launch_bounds__(256) void wprep_kernel(
    const float* __restrict__ W1, const float* __restrict__ W2,
    const float* __restrict__ emb, unsigned short* __restrict__ W1t,
    unsigned short* __restrict__ W2t) {
  __shared__ float tile[32][33];
  int bx = blockIdx.x;
  int nb = blockIdx.y * 32;
  int tx = threadIdx.x & 31, ty = threadIdx.x >> 5;
  if (bx < KX / 32) {
    int kb = bx * 32;
#pragma unroll
    for (int i = 0; i < 32; i += 8) {
      int k = kb + ty + i;
      float v = 0.f;
      if (k < 13) {
        float s = 0.f;
#pragma unroll 8
        for (int d = 0; d < 64; ++d)
          s += emb[k * 64 + d] * W1[(size_t)(k * 64 + d) * NH + nb + tx];
        v = s;
      } else if (k >= 16 && k < 1680) {
        v = W1[(size_t)(832 + k - 16) * NH + nb + tx];
      } else if (k >= 1680 && k < 1680 + NPAIR) {
        v = W1[(size_t)(2496 + k - 1680) * NH + nb + tx];
      }
      tile[ty + i][tx] = v;
    }
    __syncthreads();
#pragma unroll
    for (int i = 0; i < 32; i += 8)
      W1t[(size_t)(nb + ty + i) * KX + kb + tx] = f2bf(tile[tx][ty + i]);
  } else {
    int kb = (bx - KX / 32) * 32;
#pragma unroll
    for (int i = 0; i < 32; i += 8)
      tile[ty + i][tx] = W2[(size_t)(kb + ty + i) * NH + nb + tx];
    __syncthreads();
#pragma unroll
    for (int i = 0; i < 32; i += 8)
      W2t[(size_t)(nb + ty + i) * NH + kb + tx] = f2bf(tile[tx][ty + i]);
  }
}

// ---- features -> X' rows: [conts 13 | 0 | cate flat 1664 | pairs 741 | 0]
__global__ __launch_bounds__(256) void feature_kernel(
    const float* __restrict__ conts, const int* __restrict__ cates,
    const float* __restrict__ emb, unsigned short* __restrict__ X) {
  __shared__ unsigned short cc[4][48 * CCLD];
  __shared__ unsigned short pb[4][752];
  int wid = threadIdx.x >> 6, lane = threadIdx.x & 63;
  int b = (blockIdx.x << 2) | wid;
  unsigned short* my = cc[wid];
  unsigned short* pw = pb[wid];
  unsigned short* Xrow = X + (size_t)b * KX;

#pragma unroll
  for (int f = 0; f < 13; ++f)
    my[f * CCLD + lane] = f2bf(emb[f * 64 + lane] * conts[b * 13 + f]);
#pragma unroll 2
  for (int j = 0; j < 26; ++j) {
    int idx = cates[b * 26 + j];
    my[(13 + j) * CCLD + lane] = f2bf(emb[(size_t)idx * 64 + lane]);
  }
#pragma unroll
  for (int f = NF; f < 48; ++f) my[f * CCLD + lane] = 0;
  if (lane < 16) Xrow[lane] = (lane < 13) ? f2bf(conts[b * 13 + lane]) : 0;
  if (lane < 752 - NPAIR) pw[NPAIR + lane] = 0;
  __syncthreads();

  // cate flat: 1664 shorts = 208 x bf16x8
#pragma unroll
  for (int i = 0; i < 4; ++i) {
    int q = i * 64 + lane;
    if (q < 208)
      *(bf16x8*)&Xrow[16 + q * 8] =
          *(const bf16x8*)&my[(13 + (q >> 3)) * CCLD + (q & 7) * 8];
  }

  // gram via MFMA (frag is both A and B operand)
  int r15 = lane & 15, hi = lane >> 4;
  bf16x8 fr[2][3];
#pragma unroll
  for (int t = 0; t < 3; ++t)
#pragma unroll
    for (int h = 0; h < 2; ++h)
      fr[h][t] = *(const bf16x8*)&my[(t * 16 + r15) * CCLD + h * 32 + hi * 8];

  f32x4 acc[3][3];
#pragma unroll
  for (int it = 0; it < 3; ++it)
#pragma unroll
    for (int jt = 0; jt < 3; ++jt)
      acc[it][jt] = (f32x4){0.f, 0.f, 0.f, 0.f};
#pragma unroll
  for (int h = 0; h < 2; ++h)
#pragma unroll
    for (int it = 0; it < 3; ++it)
#pragma unroll
      for (int jt = 0; jt < 3; ++jt)
        acc[it][jt] = __builtin_amdgcn_mfma_f32_16x16x32_bf16(
            fr[h][it], fr[h][jt], acc[it][jt], 0, 0, 0);

#pragma unroll
  for (int it = 0; it < 3; ++it)
#pragma unroll
    for (int jt = 0; jt < 3; ++jt) {
      int g = jt * 16 + r15;
#pragma unroll
      for (int r = 0; r < 4; ++r) {
        int f = it * 16 + hi * 4 + r;
        if (f < g && g < NF) {
          int p = f * 38 - ((f * (f - 1)) >> 1) + g - f - 1;
          pw[p] = f2bf(acc[it][jt][r]);
        }
      }
    }
  __syncthreads();

#pragma unroll
  for (int i = 0; i < 2; ++i) {
    int q = i * 64 + lane;
    if (q < 94)
      *(bf16x8*)&Xrow[1680 + q * 8] = *(const bf16x8*)&pw[q * 8];
  }
}

// ============ 256x256 GEMM: r3 barrier/STG/vmcnt structure + in-tile read-ahead ============
// Hout(M x 1024 bf16) = A(M x K bf16)*Bt(1024 x K bf16)^T + bias. K mult of 64, NT even.
// vs r3 (verbatim barriers/STG/vmcnt): read issuance moved so LDS pipe overlaps MFMA:
//  ph0: rd B01(t)->bS;               Q0(a0,bS)   [a0 preloaded in prev ph3, behind the
//  ph1: rd B23->bR, A4-7->a1;        Q1(a0,bR)    same vmcnt(4)+barrier r3 relied on]
//  ph2: (no reads)                   Q2(a1,bR)   [a1 hidden under Q1 via lgkm(8)]
//  ph3: vmcnt(4);BAR; rd a0<=A0-3(t+1); Q3(a1,bS) [reads overlap Q3; bank-separate]
// Max 12 outstanding ds_reads per wave. Register deps additionally compiler-guarded.

#define GLL(s_, d_) __builtin_amdgcn_global_load_lds((gptr_t)(s_), (lptr_t)(d_), 16, 0, 0)
#define RD(p_) (*(const bf16x8*)(p_))
#define DSTA(buf, h) (lds + (buf) * 32768 + (h) * 8192 + sd)
#define DSTB(buf, h) (lds + (buf) * 32768 + 16384 + (h) * 8192 + sd)
#define STG(dst, srcb, tau) do { \
    const unsigned short* _s = (srcb) + (size_t)(tau) * 64; \
    GLL(_s, dst); GLL(_s + (size_t)64 * K, (dst) + 4096); } while (0)
#define PHASE_BAR() do { \
    __builtin_amdgcn_s_barrier(); \
    asm volatile("s_waitcnt lgkmcnt(0)" ::: "memory"); \
    __builtin_amdgcn_sched_barrier(0); \
    __builtin_amdgcn_s_setprio(1); } while (0)
#define PHASE_END() do { \
    __builtin_amdgcn_s_setprio(0); \
    __builtin_amdgcn_s_barrier(); \
    __builtin_amdgcn_sched_barrier(0); } while (0)

#define MQ(I0, J0, AB, BB) do { \
    _Pragma("unroll") \
    for (int i_ = 0; i_ < 4; ++i_) \
      _Pragma("unroll") \
      for (int j_ = 0; j_ < 2; ++j_) { \
        acc[(I0) + i_][(J0) + j_] = __builtin_amdgcn_mfma_f32_16x16x32_bf16( \
            AB[i_][0], BB[j_][0], acc[(I0) + i_][(J0) + j_], 0, 0, 0); \
        acc[(I0) + i_][(J0) + j_] = __builtin_amdgcn_mfma_f32_16x16x32_bf16( \
            AB[i_][1], BB[j_][1], acc[(I0) + i_][(J0) + j_], 0, 0, 0); \
      } } while (0)

__global__ __launch_bounds__(512, 2) void gemm_8ph(
    const unsigned short* __restrict__ A, const unsigned short* __restrict__ Bt,
    const float* __restrict__ bias, unsigned short* __restrict__ Hout,
    int K, int NT) {
  __shared__ unsigned short lds[65536];  // 128 KiB

  int bid = blockIdx.x;
  int swz = (bid & 7) * 32 + (bid >> 3);  // 256 wgs, 8 XCDs, chunked (bijective)
  int mb = swz >> 2, nb = swz & 3;
  size_t m0 = (size_t)mb * 256, n0 = (size_t)nb * 256;

  int tid = threadIdx.x, lane = tid & 63, w = tid >> 6;
  int wr = w >> 2, wc = w & 3;
  int r15 = lane & 15, hi = lane >> 4;

  int sr = tid >> 3;
  int ce = ((tid & 7) ^ (sr & 7)) << 3;   // inverse-swizzled global col group
  int sd = tid * 8;                        // linear LDS dest (shorts)
  const unsigned short* A0p = A + (m0 + sr) * (size_t)K + ce;
  const unsigned short* A1p = A0p + (size_t)128 * K;
  const unsigned short* B0p = Bt + (n0 + sr) * (size_t)K + ce;
  const unsigned short* B1p = B0p + (size_t)128 * K;

  int cbs = (((hi << 4) ^ ((r15 & 7) << 4)) >> 1);  // swizzled read col (shorts)
  int rb0 = r15 * 64 + cbs;
  int rb1 = rb0 ^ 32;
  const unsigned short* aH = lds + wr * 8192;
  const unsigned short* bH = lds + 16384 + (wc >> 1) * 8192 + (wc & 1) * 4096;

  f32x4 acc[8][4];
#pragma unroll
  for (int m = 0; m < 8; ++m)
#pragma unroll
    for (int n = 0; n < 4; ++n) acc[m][n] = (f32x4){0.f, 0.f, 0.f, 0.f};

  bf16x8 a0[4][2], a1[4][2], bS[2][2], bR[2][2];

  // ---- prologue (r3 + a0 preload): stage A(0),B(0),B(1); vmcnt(4); barrier; rd a0<=A0-3(0)
  {
    int t1 = (NT > 1) ? 1 : 0;
    STG(DSTB(0, 0), B0p, 0);
    STG(DSTB(0, 1), B1p, 0);
    STG(DSTA(0, 0), A0p, 0);
    STG(DSTA(0, 1), A1p, 0);
    STG(DSTB(1, 0), B0p, t1);
    STG(DSTB(1, 1), B1p, t1);
    asm volatile("s_waitcnt vmcnt(4)" ::: "memory");
    __builtin_amdgcn_s_barrier();
    __builtin_amdgcn_sched_barrier(0);
#pragma unroll
    for (int i = 0; i < 4; ++i) {
      a0[i][0] = RD(aH + i * 1024 + rb0);
      a0[i][1] = RD(aH + i * 1024 + rb1);
    }
  }

  for (int t = 0; t < NT; ++t) {
    int cur = t & 1, nxt = cur ^ 1;
    int ta = (t + 1 < NT) ? t + 1 : NT - 1;  // clamped dummies stay in-bounds
    int tb = (t + 2 < NT) ? t + 2 : NT - 1;
    const unsigned short* aBn = aH + nxt * 32768;
    const unsigned short* bB = bH + cur * 32768;

    // phase 0: rd B01(t)->bS; STG A-half0(t+1); Q0 = (m0-3, n0-1) on (a0, bS)
#pragma unroll
    for (int j = 0; j < 2; ++j) {
      bS[j][0] = RD(bB + j * 1024 + rb0);
      bS[j][1] = RD(bB + j * 1024 + rb1);
    }
    STG(DSTA(nxt, 0), A0p, ta);
    PHASE_BAR();
    MQ(0, 0, a0, bS);
    PHASE_END();

    // phase 1: rd B23->bR then A4-7->a1 (12 issued); STG A-half1(t+1);
    // wait lgkm(8) => bR done, a1 hidden under Q1. Q1 = (m0-3, n2-3) on (a0, bR)
#pragma unroll
    for (int j = 0; j < 2; ++j) {
      bR[j][0] = RD(bB + (2 + j) * 1024 + rb0);
      bR[j][1] = RD(bB + (2 + j) * 1024 + rb1);
    }
#pragma unroll
    for (int i = 0; i < 4; ++i) {
      a1[i][0] = RD(aH + cur * 32768 + (4 + i) * 1024 + rb0);
      a1[i][1] = RD(aH + cur * 32768 + (4 + i) * 1024 + rb1);
    }
    STG(DSTA(nxt, 1), A1p, ta);
    __builtin_amdgcn_s_barrier();
    asm volatile("s_waitcnt lgkmcnt(8)" ::: "memory");
    __builtin_amdgcn_sched_barrier(0);
    __builtin_amdgcn_s_setprio(1);
    MQ(0, 2, a0, bR);
    PHASE_END();

    // phase 2: STG B-half0(t+2); Q2 = (m4-7, n2-3) on (a1, bR)  [a1 completed during Q1]
    STG(DSTB(cur, 0), B0p, tb);
    PHASE_BAR();
    MQ(4, 2, a1, bR);
    PHASE_END();

    // phase 3: STG B-half1(t+2); vmcnt(4); BARRIER (same guarantee point r3 used for
    // next-tile reads); then rd a0 <= A0-3(t+1) overlapped with Q3 = (m4-7, n0-1)
    STG(DSTB(cur, 1), B1p, tb);
    asm volatile("s_waitcnt vmcnt(4)" ::: "memory");
    __builtin_amdgcn_s_barrier();
#pragma unroll
    for (int i = 0; i < 4; ++i) {
      a0[i][0] = RD(aBn + i * 1024 + rb0);
      a0[i][1] = RD(aBn + i * 1024 + rb1);
    }
    __builtin_amdgcn_sched_barrier(0);
    __builtin_amdgcn_s_setprio(1);
    MQ(4, 0, a1, bS);
    PHASE_END();
  }

  // epilogue: +bias, bf16 store. C/D: col=lane&15, row=(lane>>4)*4+q
  size_t crow = m0 + (size_t)wr * 128 + hi * 4;
  size_t ccol = n0 + (size_t)wc * 64 + r15;
  unsigned short* Hp = Hout + crow * NH + ccol;
  float bv[4];
#pragma unroll
  for (int n = 0; n < 4; ++n) bv[n] = bias[ccol + n * 16];
#pragma unroll
  for (int m = 0; m < 8; ++m)
#pragma unroll
    for (int n = 0; n < 4; ++n)
#pragma unroll
      for (int q = 0; q < 4; ++q)
        Hp[(size_t)(m * 16 + q) * NH + n * 16] = f2bf(acc[m][n][q] + bv[n]);
}

// ---- layernorm + relu, wave-per-row (16 elems/lane), no LDS / no block sync
__global__ __launch_bounds__(256) void ln_relu_kernel(
    const unsigned short* __restrict__ Yb, const float* __restrict__ gamma,
    const float* __restrict__ beta, unsigned short* __restrict__ H) {
  int wid = threadIdx.x >> 6, lane = threadIdx.x & 63;
  int b = (blockIdx.x << 2) | wid;
  const unsigned short* yrow = Yb + (size_t)b * NH + lane * 16;
  bf16x8 u0 = *(const bf16x8*)&yrow[0];
  bf16x8 u1 = *(const bf16x8*)&yrow[8];
  float v[16];
#pragma unroll
  for (int i = 0; i < 8; ++i) {
    v[i] = bf2f((unsigned short)u0[i]);
    v[8 + i] = bf2f((unsigned short)u1[i]);
  }
  float s1 = 0.f, s2 = 0.f;
#pragma unroll
  for (int i = 0; i < 16; ++i) { s1 += v[i]; s2 += v[i] * v[i]; }
#pragma unroll
  for (int i = 1; i < 64; i <<= 1) {
    s1 += __shfl_xor(s1, i);
    s2 += __shfl_xor(s2, i);
  }
  float mu = s1 * (1.0f / NH);
  float var = s2 * (1.0f / NH) - mu * mu;
  float rs = rsqrtf(var + 1e-5f);
  const float4* gp = (const float4*)(gamma + lane * 16);
  const float4* bp = (const float4*)(beta + lane * 16);
  unsigned short o[16];
#pragma unroll
  for (int q = 0; q < 4; ++q) {
    float4 gg = gp[q], be = bp[q];
    o[q * 4 + 0] = f2bf(fmaxf((v[q * 4 + 0] - mu) * rs * gg.x + be.x, 0.f));
    o[q * 4 + 1] = f2bf(fmaxf((v[q * 4 + 1] - mu) * rs * gg.y + be.y, 0.f));
    o[q * 4 + 2] = f2bf(fmaxf((v[q * 4 + 2] - mu) * rs * gg.z + be.z, 0.f));
    o[q * 4 + 3] = f2bf(fmaxf((v[q * 4 + 3] - mu) * rs * gg.w + be.w, 0.f));
  }
  unsigned short* hrow = H + (size_t)b * NH + lane * 16;
  *(ulonglong2*)&hrow[0] = *(const ulonglong2*)&o[0];
  *(ulonglong2*)&hrow[8] = *(const ulonglong2*)&o[8];
}

// ---- layernorm + relu + dot(Wout) + sigmoid, wave-per-row
__global__ __launch_bounds__(256) void ln_out_kernel(
    const unsigned short* __restrict__ Yb, const float* __restrict__ gamma,
    const float* __restrict__ beta, const float* __restrict__ Wout,
    const float* __restrict__ bout, float* __restrict__ out) {
  int wid = threadIdx.x >> 6, lane = threadIdx.x & 63;
  int b = (blockIdx.x << 2) | wid;
  const unsigned short* yrow = Yb + (size_t)b * NH + lane * 16;
  bf16x8 u0 = *(const bf16x8*)&yrow[0];
  bf16x8 u1 = *(const bf16x8*)&yrow[8];
  float v[16];
#pragma unroll
  for (int i = 0; i < 8; ++i) {
    v[i] = bf2f((unsigned short)u0[i]);
    v[8 + i] = bf2f((unsigned short)u1[i]);
  }
  float s1 = 0.f, s2 = 0.f;
#pragma unroll
  for (int i = 0; i < 16; ++i) { s1 += v[i]; s2 += v[i] * v[i]; }
#pragma unroll
  for (int i = 1; i < 64; i <<= 1) {
    s1 += __shfl_xor(s1, i);
    s2 += __shfl_xor(s2, i);
  }
  float mu = s1 * (1.0f / NH);
  float var = s2 * (1.0f / NH) - mu * mu;
  float rs = rsqrtf(var + 1e-5f);
  const float4* gp = (const float4*)(gamma + lane * 16);
  const float4* bp = (const float4*)(beta + lane * 16);
  const float4* wp = (const float4*)(Wout + lane * 16);
  float s = 0.f;
#pragma unroll
  for (int q = 0; q < 4; ++q) {
    float4 gg = gp[q], be = bp[q], wo = wp[q];
    s += fmaxf((v[q * 4 + 0] - mu) * rs * gg.x + be.x, 0.f) * wo.x;
    s += fmaxf((v[q * 4 + 1] - mu) * rs * gg.y + be.y, 0.f) * wo.y;
    s += fmaxf((v[q * 4 + 2] - mu) * rs * gg.z + be.z, 0.f) * wo.z;
    s += fmaxf((v[q * 4 + 3] - mu) * rs * gg.w + be.w, 0.f) * wo.w;
  }
#pragma unroll
  for (int i = 1; i < 64; i <<= 1) s += __shfl_xor(s, i);
  if (lane == 0) out[b] = 1.f / (1.f + expf(-(s + bout[0])));
}

extern "C" void kernel_launch(void* const* d_in, const int* in_sizes, int n_in,
                              void* d_out, int out_size, void* d_ws, size_t ws_size,
                              hipStream_t stream) {
  const float* conts = (const float*)d_in[0];
  const int* cates = (const int*)d_in[1];
  const float* emb  = (const float*)d_in[3];
  const float* W1   = (const float*)d_in[4];
  const float* b1   = (const float*)d_in[5];
  const float* ln1g = (const float*)d_in[6];
  const float* ln1b = (const float*)d_in[7];
  const float* W2   = (const float*)d_in[8];
  const float* b2   = (const float*)d_in[9];
  const float* ln2g = (const float*)d_in[10];
  const float* ln2b = (const float*)d_in[11];
  const float* Wout = (const float*)d_in[12];
  const float* bout = (const float*)d_in[13];
  float* out = (float*)d_out;

  unsigned short* X   = (unsigned short*)d_ws;            // BATCH * KX
  unsigned short* W1t = X + (size_t)BATCH * KX;           // NH * KX
  unsigned short* W2t = W1t + (size_t)NH * KX;            // NH * NH
  unsigned short* H1  = W2t + (size_t)NH * NH;            // BATCH * NH
  unsigned short* Yb1 = H1 + (size_t)BATCH * NH;          // BATCH * NH
  unsigned short* Yb2 = Yb1 + (size_t)BATCH * NH;         // BATCH * NH

  hipLaunchKernelGGL(wprep_kernel, dim3(KX / 32 + NH / 32, NH / 32), dim3(256), 0, stream,
                     W1, W2, emb, W1t, W2t);
  hipLaunchKernelGGL(feature_kernel, dim3(BATCH / 4), dim3(256), 0, stream,
                     conts, cates, emb, X);
  hipLaunchKernelGGL(gemm_8ph, dim3(256), dim3(512), 0, stream,
                     X, W1t, b1, Yb1, KX, KX / 64);
  hipLaunchKernelGGL(ln_relu_kernel, dim3(BATCH / 4), dim3(256), 0, stream,
                     Yb1, ln1g, ln1b, H1);
  hipLaunchKernelGGL(gemm_8ph, dim3(256), dim3(512), 0, stream,
                     H1, W2t, b2, Yb2, NH, NH / 64);
  hipLaunchKernelGGL(ln_out_kernel, dim3(BATCH / 4), dim3(256), 0, stream,
                     Yb2, ln2g, ln2b, Wout, bout, out);
}